// Round 1
// baseline (1087.239 us; speedup 1.0000x reference)
//
#include <hip/hip_runtime.h>
#include <hip/hip_fp16.h>

constexpr int B = 2, H = 12, S = 2048, D = 64;
constexpr int TQ = 16;            // query rows per block
constexpr int PADH = 18;          // halves per LDS score row (pad vs 16)
constexpr int NBLK_Q = S / TQ;    // 128

__global__ __launch_bounds__(256, 2)
void sparsemax_attn_kernel(const float* __restrict__ Q, const float* __restrict__ K,
                           const float* __restrict__ V, const float* __restrict__ mask,
                           const float* __restrict__ scale, float* __restrict__ out)
{
    __shared__ alignas(16) __half s_sh[S * PADH];   // 73728 B: scores -> probs -> (reused) reduction
    __shared__ float tau_s[TQ];

    const int tid  = threadIdx.x;
    const int lane = tid & 63;
    const int w    = tid >> 6;              // wave 0..3
    const int bh   = blockIdx.x / NBLK_Q;
    const int qt   = blockIdx.x - bh * NBLK_Q;
    const int b    = bh / H;
    const int h    = bh - b * H;
    const int q0   = qt * TQ;

    const size_t bhSD = (size_t)bh * S * D;
    const float* Qblk = Q + bhSD + (size_t)q0 * D;
    const float* Kbh  = K + bhSD;
    const float* Vbh  = V + bhSD;
    const float* mrow = mask + (size_t)b * S;
    const float  sc   = __expf(scale[h]) * 0.125f;   // exp(scale)/sqrt(64)

    // ---------------- Phase 1: scores = QK^T*sc + maskterm, fp16 -> LDS ----------------
    // wave w handles key tiles t = w*8 .. w*8+7 (64 keys each); lane owns one K row.
    {
        float4 ka[16], kb[16];
        float adda = 0.f, addb = 0.f;
        const int t0 = w * 8;
#define LOADK(buf, addv, ti) { \
            const int kk = ((t0 + (ti)) << 6) + lane; \
            const float4* kp = (const float4*)(Kbh + (size_t)kk * D); \
            _Pragma("unroll") for (int j = 0; j < 16; ++j) buf[j] = kp[j]; \
            addv = (1.0f - mrow[kk]) * -3.402823466e38f; }
#define COMPT(buf, addv, ti) { \
            const int kk = ((t0 + (ti)) << 6) + lane; \
            _Pragma("unroll") for (int q = 0; q < 16; ++q) { \
                const float* qr = Qblk + q * D; /* wave-uniform -> s_load */ \
                float acc = 0.f; \
                _Pragma("unroll") for (int j = 0; j < 16; ++j) { \
                    acc += qr[4*j+0] * buf[j].x; \
                    acc += qr[4*j+1] * buf[j].y; \
                    acc += qr[4*j+2] * buf[j].z; \
                    acc += qr[4*j+3] * buf[j].w; } \
                s_sh[(size_t)kk * PADH + q] = __float2half(acc * sc + (addv)); } }

        LOADK(ka, adda, 0)
        for (int i = 0; i < 8; i += 2) {
            LOADK(kb, addb, i + 1)
            COMPT(ka, adda, i)
            if (i + 2 < 8) LOADK(ka, adda, i + 2)
            COMPT(kb, addb, i + 1)
        }
#undef LOADK
#undef COMPT
    }
    __syncthreads();

    // ---------------- Phase 2: exact sparsemax tau via Newton on f(tau)=sum(max(z-tau,0))-1 ----
    // wave w handles q rows w*4 .. w*4+3; lane holds 32 scores of the row.
    for (int r = 0; r < 4; ++r) {
        const int q = w * 4 + r;
        float z[32];
        #pragma unroll
        for (int j = 0; j < 32; ++j)
            z[j] = __half2float(s_sh[(size_t)(j * 64 + lane) * PADH + q]);
        float m = z[0];
        #pragma unroll
        for (int j = 1; j < 32; ++j) m = fmaxf(m, z[j]);
        #pragma unroll
        for (int off = 32; off >= 1; off >>= 1) m = fmaxf(m, __shfl_xor(m, off));
        float tau = m - 1.0f;                 // f(tau0) >= 0; Newton increases tau monotonically
        for (int it = 0; it < 32; ++it) {
            float s1 = 0.f;
            int   cnt = 0;
            #pragma unroll
            for (int j = 0; j < 32; ++j) {
                const float dlt = z[j] - tau;
                s1 += fmaxf(dlt, 0.f);
                cnt += (int)__popcll(__ballot(dlt > 0.f));   // wave-global support count
            }
            #pragma unroll
            for (int off = 32; off >= 1; off >>= 1) s1 += __shfl_xor(s1, off);
            const float tn = tau + (s1 - 1.0f) / (float)cnt;
            if (!(tn > tau)) break;           // converged exactly (support stable)
            tau = tn;
        }
        if (lane == 0) tau_s[q] = tau;
    }
    __syncthreads();

    // ---------------- Phase 2.5: scores -> probs in place (fp16) ----------------
    {
        float tl[16];
        #pragma unroll
        for (int qq = 0; qq < 16; ++qq) tl[qq] = tau_s[qq];
        for (int j = 0; j < 8; ++j) {
            const int k = tid + 256 * j;
            __half* row = &s_sh[(size_t)k * PADH];
            #pragma unroll
            for (int qq = 0; qq < 16; ++qq) {
                const float p = __half2float(row[qq]) - tl[qq];
                row[qq] = __float2half(fmaxf(p, 0.f));
            }
        }
    }
    __syncthreads();

    // ---------------- Phase 3: out = P.V ; waves split k-range, lane owns 4q x 4d tile ------
    const int qi = lane >> 4;     // 0..3 -> q block qi*4..qi*4+3
    const int di = lane & 15;     // 0..15 -> d block di*4..di*4+3
    float acc[4][4] = {};
    {
        const int kbeg = w * (S / 4);
        const float4* V4 = (const float4*)Vbh;
        #pragma unroll 4
        for (int k = kbeg; k < kbeg + S / 4; ++k) {
            const float4 v = V4[(size_t)k * 16 + di];                       // coalesced 256B/row
            const __half2* pr = (const __half2*)(s_sh + (size_t)k * PADH + 4 * qi);
            const float2 p01 = __half22float2(pr[0]);
            const float2 p23 = __half22float2(pr[1]);
            const float pv[4] = { p01.x, p01.y, p23.x, p23.y };
            const float vv[4] = { v.x, v.y, v.z, v.w };
            #pragma unroll
            for (int a = 0; a < 4; ++a)
                #pragma unroll
                for (int c = 0; c < 4; ++c)
                    acc[a][c] += pv[a] * vv[c];
        }
    }
    __syncthreads();   // probs fully consumed; safe to reuse LDS

    // cross-wave reduction of the 4 k-partials through LDS
    float* red = reinterpret_cast<float*>(s_sh);        // [4][16][64] f32 = 16 KB
    #pragma unroll
    for (int a = 0; a < 4; ++a)
        #pragma unroll
        for (int c = 0; c < 4; ++c)
            red[((w * 16) + (qi * 4 + a)) * 64 + (di * 4 + c)] = acc[a][c];
    __syncthreads();

    #pragma unroll
    for (int g = 0; g < 4; ++g) {
        const int q = g * 4 + w;
        const int d = lane;
        const float sum = red[(0 * 16 + q) * 64 + d] + red[(1 * 16 + q) * 64 + d]
                        + red[(2 * 16 + q) * 64 + d] + red[(3 * 16 + q) * 64 + d];
        out[bhSD + (size_t)(q0 + q) * D + d] = sum;
    }
}

extern "C" void kernel_launch(void* const* d_in, const int* in_sizes, int n_in,
                              void* d_out, int out_size, void* d_ws, size_t ws_size,
                              hipStream_t stream) {
    const float* Q     = (const float*)d_in[0];
    const float* K     = (const float*)d_in[1];
    const float* V     = (const float*)d_in[2];
    const float* mask  = (const float*)d_in[3];
    const float* scale = (const float*)d_in[4];
    float* out = (float*)d_out;
    sparsemax_attn_kernel<<<dim3(B * H * NBLK_Q), dim3(256), 0, stream>>>(
        Q, K, V, mask, scale, out);
}

// Round 2
// 237.548 us; speedup vs baseline: 4.5769x; 4.5769x over previous
//
#include <hip/hip_runtime.h>
#include <hip/hip_fp16.h>

constexpr int B = 2, H = 12, S = 2048, D = 64;
constexpr int TQ = 16;            // query rows per block
constexpr int PADH = 18;          // halves per LDS score row (pad vs 16)
constexpr int NBLK_Q = S / TQ;    // 128
constexpr size_t BHSD = (size_t)B * H * S * D;   // 3,145,728 elements

using f16x8 = _Float16 __attribute__((ext_vector_type(8)));
using f16x4 = _Float16 __attribute__((ext_vector_type(4)));
using f32x4 = float __attribute__((ext_vector_type(4)));

// ---------------- pre-pass: K fp32 -> f16 (same [bh][k][d] layout) ----------------
__global__ __launch_bounds__(256)
void cvt_k_kernel(const float* __restrict__ K, _Float16* __restrict__ Kh) {
    const size_t i = ((size_t)blockIdx.x * 256 + threadIdx.x) * 4;
    const float4 x = *reinterpret_cast<const float4*>(K + i);
    f16x4 y;
    y[0] = (_Float16)x.x; y[1] = (_Float16)x.y; y[2] = (_Float16)x.z; y[3] = (_Float16)x.w;
    *reinterpret_cast<f16x4*>(Kh + i) = y;
}

// ---------------- pre-pass: V fp32 [bh][k][d] -> f16 transposed [bh][d][k] -------
__global__ __launch_bounds__(256)
void tr_v_kernel(const float* __restrict__ V, _Float16* __restrict__ Vt) {
    __shared__ alignas(16) _Float16 tl[64][68];
    const int bh = blockIdx.x >> 5;
    const int k0 = (blockIdx.x & 31) * 64;
    const int tid = threadIdx.x;
    const int d4 = tid & 15, kl = tid >> 4;     // read: 16 float4-cols x 16 rows
    const float* Vb = V + (size_t)bh * S * D;
    #pragma unroll
    for (int i = 0; i < 4; ++i) {
        const int k = kl + 16 * i;
        const float4 x = *reinterpret_cast<const float4*>(Vb + (size_t)(k0 + k) * D + d4 * 4);
        f16x4 y;
        y[0] = (_Float16)x.x; y[1] = (_Float16)x.y; y[2] = (_Float16)x.z; y[3] = (_Float16)x.w;
        *reinterpret_cast<f16x4*>(&tl[k][d4 * 4]) = y;
    }
    __syncthreads();
    const int d = tid >> 2;                     // 0..63
    _Float16* Vtb = Vt + (size_t)bh * D * S + (size_t)d * S + k0;
    #pragma unroll
    for (int i = 0; i < 2; ++i) {
        const int kloc = ((tid & 3) * 2 + i) * 8;
        f16x8 v;
        #pragma unroll
        for (int j = 0; j < 8; ++j) v[j] = tl[kloc + j][d];
        *reinterpret_cast<f16x8*>(Vtb + kloc) = v;
    }
}

// ---------------- main fused kernel ----------------
template <bool PRE>
__global__ __launch_bounds__(256, 2)
void sparsemax_attn_kernel(const float* __restrict__ Q, const float* __restrict__ K,
                           const float* __restrict__ V, const float* __restrict__ mask,
                           const float* __restrict__ scale, float* __restrict__ out,
                           const _Float16* __restrict__ Kh, const _Float16* __restrict__ Vt)
{
    __shared__ alignas(16) _Float16 s_sh[S * PADH];   // 73728 B: scores, then f32 reduction
    __shared__ float tau_s[TQ];

    const int tid  = threadIdx.x;
    const int lane = tid & 63;
    const int w    = tid >> 6;              // wave 0..3
    const int row  = lane & 15;             // frag row/col index
    const int grp  = lane >> 4;             // frag k-group 0..3
    const int bh   = blockIdx.x / NBLK_Q;
    const int qt   = blockIdx.x - bh * NBLK_Q;
    const int b    = bh / H;
    const int h    = bh - b * H;
    const int q0   = qt * TQ;

    const size_t bhSD = (size_t)bh * S * D;
    const float* mrow = mask + (size_t)b * S;
    const float  sc   = __expf(scale[h]) * 0.125f;   // exp(scale)/sqrt(64)

    // ---- Q A-fragments (16 x 64, two K=32 chunks): Q[q0+row][c*32 + grp*8 + j] ----
    f16x8 qa[2];
    {
        const float* qr = Q + bhSD + (size_t)(q0 + row) * D + grp * 8;
        #pragma unroll
        for (int c = 0; c < 2; ++c) {
            const float4 x0 = *reinterpret_cast<const float4*>(qr + c * 32);
            const float4 x1 = *reinterpret_cast<const float4*>(qr + c * 32 + 4);
            qa[c][0] = (_Float16)x0.x; qa[c][1] = (_Float16)x0.y;
            qa[c][2] = (_Float16)x0.z; qa[c][3] = (_Float16)x0.w;
            qa[c][4] = (_Float16)x1.x; qa[c][5] = (_Float16)x1.y;
            qa[c][6] = (_Float16)x1.z; qa[c][7] = (_Float16)x1.w;
        }
    }

    // ---------------- Phase 1: scores = (QK^T)*sc + mask  (MFMA) ----------------
    // wave w handles 16-key tiles t = w*32 .. w*32+31
    for (int t = w * 32; t < w * 32 + 32; ++t) {
        const int key0 = t * 16;
        const int key  = key0 + row;
        f16x8 kb0, kb1;
        if constexpr (PRE) {
            const _Float16* kp = Kh + bhSD + (size_t)key * D + grp * 8;
            kb0 = *reinterpret_cast<const f16x8*>(kp);
            kb1 = *reinterpret_cast<const f16x8*>(kp + 32);
        } else {
            const float* kp = K + bhSD + (size_t)key * D + grp * 8;
            #pragma unroll
            for (int c = 0; c < 2; ++c) {
                const float4 x0 = *reinterpret_cast<const float4*>(kp + c * 32);
                const float4 x1 = *reinterpret_cast<const float4*>(kp + c * 32 + 4);
                f16x8& kb = c ? kb1 : kb0;
                kb[0] = (_Float16)x0.x; kb[1] = (_Float16)x0.y;
                kb[2] = (_Float16)x0.z; kb[3] = (_Float16)x0.w;
                kb[4] = (_Float16)x1.x; kb[5] = (_Float16)x1.y;
                kb[6] = (_Float16)x1.z; kb[7] = (_Float16)x1.w;
            }
        }
        f32x4 acc = {0.f, 0.f, 0.f, 0.f};
        acc = __builtin_amdgcn_mfma_f32_16x16x32_f16(qa[0], kb0, acc, 0, 0, 0);
        acc = __builtin_amdgcn_mfma_f32_16x16x32_f16(qa[1], kb1, acc, 0, 0, 0);
        const float madd = (1.0f - mrow[key]) * -1.0e9f;
        // D mapping: col(=key within tile)=lane&15, row(=q)=grp*4+reg
        #pragma unroll
        for (int r = 0; r < 4; ++r) {
            const float v = fmaxf(acc[r] * sc + madd, -60000.0f);
            s_sh[(size_t)key * PADH + grp * 4 + r] = (_Float16)v;
        }
    }
    __syncthreads();

    // ---------------- Phase 2: exact tau via Newton on f(tau)=sum(max(z-tau,0))-1 ----
    for (int r = 0; r < 4; ++r) {
        const int q = w * 4 + r;
        float z[32];
        #pragma unroll
        for (int j = 0; j < 32; ++j)
            z[j] = (float)s_sh[(size_t)(j * 64 + lane) * PADH + q];
        float m = z[0];
        #pragma unroll
        for (int j = 1; j < 32; ++j) m = fmaxf(m, z[j]);
        #pragma unroll
        for (int off = 32; off >= 1; off >>= 1) m = fmaxf(m, __shfl_xor(m, off));
        float tau = m - 1.0f;
        for (int it = 0; it < 32; ++it) {
            float s1 = 0.f;
            int   cnt = 0;
            #pragma unroll
            for (int j = 0; j < 32; ++j) {
                const float dlt = z[j] - tau;
                s1 += fmaxf(dlt, 0.f);
                cnt += (int)__popcll(__ballot(dlt > 0.f));
            }
            #pragma unroll
            for (int off = 32; off >= 1; off >>= 1) s1 += __shfl_xor(s1, off);
            const float tn = tau + (s1 - 1.0f) / (float)cnt;
            if (!(tn > tau)) break;           // support stable -> exact
            tau = tn;
        }
        if (lane == 0) tau_s[q] = tau;
    }
    __syncthreads();

    // ---------------- Phase 3: out = P.V (MFMA); tau-subtract folded into A-frag ----
    const float tau_row = tau_s[row];         // this lane's q for the A fragment
    f32x4 o[4] = {{0.f,0.f,0.f,0.f},{0.f,0.f,0.f,0.f},{0.f,0.f,0.f,0.f},{0.f,0.f,0.f,0.f}};
    for (int c = w * 16; c < w * 16 + 16; ++c) {
        const int k0 = c * 32;
        f16x8 pa;
        #pragma unroll
        for (int j = 0; j < 8; ++j) {
            const float z = (float)s_sh[(size_t)(k0 + grp * 8 + j) * PADH + row];
            pa[j] = (_Float16)fmaxf(z - tau_row, 0.0f);
        }
        #pragma unroll
        for (int n = 0; n < 4; ++n) {
            f16x8 vb;
            if constexpr (PRE) {
                vb = *reinterpret_cast<const f16x8*>(
                    Vt + (size_t)bh * D * S + (size_t)(n * 16 + row) * S + k0 + grp * 8);
            } else {
                #pragma unroll
                for (int j = 0; j < 8; ++j)
                    vb[j] = (_Float16)V[bhSD + (size_t)(k0 + grp * 8 + j) * D + n * 16 + row];
            }
            o[n] = __builtin_amdgcn_mfma_f32_16x16x32_f16(pa, vb, o[n], 0, 0, 0);
        }
    }
    __syncthreads();   // probs fully consumed; reuse LDS for f32 reduction

    float* red = reinterpret_cast<float*>(s_sh);        // [4][16][64] f32 = 16 KB
    #pragma unroll
    for (int n = 0; n < 4; ++n)
        #pragma unroll
        for (int r = 0; r < 4; ++r)
            red[(w * 16 + grp * 4 + r) * 64 + n * 16 + row] = o[n][r];
    __syncthreads();

    {
        const int base = tid * 4;              // q = base/64, d = base%64
        float4 s0 = *reinterpret_cast<const float4*>(red + 0 * 1024 + base);
        const float4 s1 = *reinterpret_cast<const float4*>(red + 1 * 1024 + base);
        const float4 s2 = *reinterpret_cast<const float4*>(red + 2 * 1024 + base);
        const float4 s3 = *reinterpret_cast<const float4*>(red + 3 * 1024 + base);
        s0.x += s1.x + s2.x + s3.x;
        s0.y += s1.y + s2.y + s3.y;
        s0.z += s1.z + s2.z + s3.z;
        s0.w += s1.w + s2.w + s3.w;
        *reinterpret_cast<float4*>(out + bhSD + (size_t)q0 * D + base) = s0;
    }
}

extern "C" void kernel_launch(void* const* d_in, const int* in_sizes, int n_in,
                              void* d_out, int out_size, void* d_ws, size_t ws_size,
                              hipStream_t stream) {
    const float* Q     = (const float*)d_in[0];
    const float* K     = (const float*)d_in[1];
    const float* V     = (const float*)d_in[2];
    const float* mask  = (const float*)d_in[3];
    const float* scale = (const float*)d_in[4];
    float* out = (float*)d_out;

    const size_t need = 2 * BHSD * sizeof(_Float16);   // Kh + Vt = 12.6 MB
    if (ws_size >= need) {
        _Float16* Kh = (_Float16*)d_ws;
        _Float16* Vt = Kh + BHSD;
        cvt_k_kernel<<<dim3((unsigned)(BHSD / (256 * 4))), dim3(256), 0, stream>>>(K, Kh);
        tr_v_kernel<<<dim3(B * H * (S / 64)), dim3(256), 0, stream>>>(V, Vt);
        sparsemax_attn_kernel<true><<<dim3(B * H * NBLK_Q), dim3(256), 0, stream>>>(
            Q, K, V, mask, scale, out, Kh, Vt);
    } else {
        sparsemax_attn_kernel<false><<<dim3(B * H * NBLK_Q), dim3(256), 0, stream>>>(
            Q, K, V, mask, scale, out, nullptr, nullptr);
    }
}